// Round 1
// baseline (129.744 us; speedup 1.0000x reference)
//
#include <hip/hip_runtime.h>

// ProbabilityAdjustedLoss: B=8388608 rows of (2 logits, 1 label) -> scalar mean loss.
// Memory-bound streaming reduction: 96 MB read / ~15.3 us roofline @ 6.3 TB/s.

#define B_TOTAL   8388608
#define INV_B     (1.0f / 8388608.0f)   // power of two, exact
#define EPS_LOSS  1e-8f

__global__ void pal_zero_out(float* __restrict__ out) {
    out[0] = 0.0f;   // d_out is poisoned to 0xAA before every timed replay
}

__device__ __forceinline__ float row_loss(float l0, float l1, int label) {
    float d  = l1 - l0;
    // exact sigmoids both ways: avoids 1-p cancellation for extreme logits
    float p0 = 1.0f / (1.0f + __expf(d));    // softmax prob of class 0
    float p1 = 1.0f / (1.0f + __expf(-d));   // softmax prob of class 1
    // stop-gradient weights (forward-only here)
    float w0 = fmaxf(0.1f, 1.0f - fmaxf(0.0f, p0 - 0.95f) * 10.0f);          // /0.05*0.5
    float w1 = fmaxf(0.5f, 2.0f - fmaxf(0.0f, p1 - 0.05f) * (1.0f/0.95f));
    bool stable = (label == 0);
    float p = stable ? p0 : p1;
    float w = stable ? w0 : w1;
    return -w * __logf(p + EPS_LOSS);
}

__global__ __launch_bounds__(256) void pal_loss_kernel(
        const float4* __restrict__ lg,   // 2 rows per float4: (l0,l1,l0,l1)
        const int2*   __restrict__ lb,   // 2 labels per int2
        float* __restrict__ out,
        int n2)                          // = B/2
{
    int tid    = blockIdx.x * blockDim.x + threadIdx.x;
    int stride = gridDim.x * blockDim.x;

    float acc = 0.0f;
    for (int i = tid; i < n2; i += stride) {
        float4 L = lg[i];
        int2   Y = lb[i];
        acc += row_loss(L.x, L.y, Y.x);
        acc += row_loss(L.z, L.w, Y.y);
    }

    // wave-64 butterfly-free down-reduce
    #pragma unroll
    for (int off = 32; off > 0; off >>= 1)
        acc += __shfl_down(acc, off, 64);

    __shared__ float wsum[4];            // 256 threads = 4 waves
    int lane = threadIdx.x & 63;
    int wid  = threadIdx.x >> 6;
    if (lane == 0) wsum[wid] = acc;
    __syncthreads();

    if (threadIdx.x == 0) {
        float s = wsum[0] + wsum[1] + wsum[2] + wsum[3];
        atomicAdd(out, s * INV_B);       // 2048 atomics total, device-scope
    }
}

extern "C" void kernel_launch(void* const* d_in, const int* in_sizes, int n_in,
                              void* d_out, int out_size, void* d_ws, size_t ws_size,
                              hipStream_t stream) {
    const float4* lg  = (const float4*)d_in[0];   // logits f32 (B,2) -> B/2 float4
    const int2*   lb  = (const int2*)d_in[1];     // labels int32 (B,) -> B/2 int2
    float*        out = (float*)d_out;

    int n2 = B_TOTAL / 2;                         // 4,194,304

    pal_zero_out<<<1, 1, 0, stream>>>(out);

    dim3 grid(2048), block(256);                  // 8192 waves: full occupancy, grid-stride
    pal_loss_kernel<<<grid, block, 0, stream>>>(lg, lb, out, n2);
}

// Round 2
// 125.672 us; speedup vs baseline: 1.0324x; 1.0324x over previous
//
#include <hip/hip_runtime.h>

// ProbabilityAdjustedLoss: B=8388608 rows of (2 logits, 1 label) -> scalar mean loss.
// Memory/latency-bound streaming reduction. 96 MB input footprint (64 MB logits f32,
// 32 MB labels i32). Key change vs R0: compile-time trip count (8) + full unroll so
// all 16 loads/thread are in flight at once (R0 was 8 serialized load->use rounds,
// 44 us @ 14% HBM, VALUBusy 26% -> latency-bound).

#define B_TOTAL   8388608
#define INV_B     (1.0f / 8388608.0f)   // power of two, exact
#define EPS_LOSS  1e-8f

#define NBLOCK    2048
#define NTHREAD   256
#define NTOT      (NBLOCK * NTHREAD)            // 524288 threads
#define NITER     (B_TOTAL / 2 / NTOT)          // 8, exact (no tail)

__global__ void pal_zero_out(float* __restrict__ out) {
    out[0] = 0.0f;   // d_out is poisoned to 0xAA before every timed replay
}

__device__ __forceinline__ float row_loss(float l0, float l1, int label) {
    float d  = l1 - l0;
    // exact sigmoids both ways: avoids 1-p cancellation for extreme logits
    float p0 = 1.0f / (1.0f + __expf(d));    // softmax prob of class 0
    float p1 = 1.0f / (1.0f + __expf(-d));   // softmax prob of class 1
    // stop-gradient weights (forward-only here)
    float w0 = fmaxf(0.1f, 1.0f - fmaxf(0.0f, p0 - 0.95f) * 10.0f);
    float w1 = fmaxf(0.5f, 2.0f - fmaxf(0.0f, p1 - 0.05f) * (1.0f/0.95f));
    bool stable = (label == 0);
    float p = stable ? p0 : p1;
    float w = stable ? w0 : w1;
    return -w * __logf(p + EPS_LOSS);
}

__global__ __launch_bounds__(NTHREAD) void pal_loss_kernel(
        const float4* __restrict__ lg,   // 2 rows per float4: (l0,l1,l0,l1)
        const int2*   __restrict__ lb,   // 2 labels per int2
        float* __restrict__ out)
{
    int tid = blockIdx.x * NTHREAD + threadIdx.x;

    // Stage all loads first: 8 float4 + 8 int2, fully coalesced (stride-1 per
    // instruction across the wave), all independent -> 16 outstanding vmem ops.
    float4 L[NITER];
    int2   Y[NITER];
    #pragma unroll
    for (int k = 0; k < NITER; ++k) {
        L[k] = lg[tid + k * NTOT];
        Y[k] = lb[tid + k * NTOT];
    }

    float acc = 0.0f;
    #pragma unroll
    for (int k = 0; k < NITER; ++k) {
        acc += row_loss(L[k].x, L[k].y, Y[k].x);
        acc += row_loss(L[k].z, L[k].w, Y[k].y);
    }

    // wave-64 down-reduce
    #pragma unroll
    for (int off = 32; off > 0; off >>= 1)
        acc += __shfl_down(acc, off, 64);

    __shared__ float wsum[NTHREAD / 64];
    int lane = threadIdx.x & 63;
    int wid  = threadIdx.x >> 6;
    if (lane == 0) wsum[wid] = acc;
    __syncthreads();

    if (threadIdx.x == 0) {
        float s = wsum[0] + wsum[1] + wsum[2] + wsum[3];
        atomicAdd(out, s * INV_B);       // 2048 atomics total, device-scope
    }
}

extern "C" void kernel_launch(void* const* d_in, const int* in_sizes, int n_in,
                              void* d_out, int out_size, void* d_ws, size_t ws_size,
                              hipStream_t stream) {
    const float4* lg  = (const float4*)d_in[0];   // logits f32 (B,2) -> B/2 float4
    const int2*   lb  = (const int2*)d_in[1];     // labels int32 (B,) -> B/2 int2
    float*        out = (float*)d_out;

    pal_zero_out<<<1, 1, 0, stream>>>(out);
    pal_loss_kernel<<<NBLOCK, NTHREAD, 0, stream>>>(lg, lb, out);
}

// Round 3
// 115.428 us; speedup vs baseline: 1.1240x; 1.0887x over previous
//
#include <hip/hip_runtime.h>

// ProbabilityAdjustedLoss: B=8388608 rows of (2 logits, 1 label) -> scalar mean loss.
// R2 theory: R0/R1 identical at ~42us despite different load schedules -> bottleneck
// is the burst of 2048 same-address atomicAdds (serialized RMW at one TCC line),
// not load ILP. Fix: block partials to d_ws (plain stores) + tiny finalize kernel.

#define B_TOTAL   8388608
#define INV_B     (1.0f / 8388608.0f)   // power of two, exact
#define EPS_LOSS  1e-8f

#define NBLOCK    2048
#define NTHREAD   256
#define NTOT      (NBLOCK * NTHREAD)            // 524288 threads
#define NITER     (B_TOTAL / 2 / NTOT)          // 8, exact (no tail)

__device__ __forceinline__ float row_loss(float l0, float l1, int label) {
    float d  = l1 - l0;
    float p0 = 1.0f / (1.0f + __expf(d));    // softmax prob of class 0
    float p1 = 1.0f / (1.0f + __expf(-d));   // softmax prob of class 1
    float w0 = fmaxf(0.1f, 1.0f - fmaxf(0.0f, p0 - 0.95f) * 10.0f);
    float w1 = fmaxf(0.5f, 2.0f - fmaxf(0.0f, p1 - 0.05f) * (1.0f/0.95f));
    bool stable = (label == 0);
    float p = stable ? p0 : p1;
    float w = stable ? w0 : w1;
    return -w * __logf(p + EPS_LOSS);
}

__global__ __launch_bounds__(NTHREAD) void pal_loss_kernel(
        const float4* __restrict__ lg,   // 2 rows per float4: (l0,l1,l0,l1)
        const int2*   __restrict__ lb,   // 2 labels per int2
        float* __restrict__ partials)    // d_ws: one float per block
{
    int tid = blockIdx.x * NTHREAD + threadIdx.x;

    float4 L[NITER];
    int2   Y[NITER];
    #pragma unroll
    for (int k = 0; k < NITER; ++k) {
        L[k] = lg[tid + k * NTOT];
        Y[k] = lb[tid + k * NTOT];
    }

    float acc = 0.0f;
    #pragma unroll
    for (int k = 0; k < NITER; ++k) {
        acc += row_loss(L[k].x, L[k].y, Y[k].x);
        acc += row_loss(L[k].z, L[k].w, Y[k].y);
    }

    // wave-64 down-reduce
    #pragma unroll
    for (int off = 32; off > 0; off >>= 1)
        acc += __shfl_down(acc, off, 64);

    __shared__ float wsum[NTHREAD / 64];
    int lane = threadIdx.x & 63;
    int wid  = threadIdx.x >> 6;
    if (lane == 0) wsum[wid] = acc;
    __syncthreads();

    if (threadIdx.x == 0)
        partials[blockIdx.x] = wsum[0] + wsum[1] + wsum[2] + wsum[3];  // no atomic
}

__global__ __launch_bounds__(NTHREAD) void pal_finalize_kernel(
        const float* __restrict__ partials,  // 2048 floats
        float* __restrict__ out)
{
    // 256 threads x 8 partials each
    float acc = 0.0f;
    #pragma unroll
    for (int k = 0; k < NBLOCK / NTHREAD; ++k)
        acc += partials[threadIdx.x + k * NTHREAD];

    #pragma unroll
    for (int off = 32; off > 0; off >>= 1)
        acc += __shfl_down(acc, off, 64);

    __shared__ float wsum[NTHREAD / 64];
    int lane = threadIdx.x & 63;
    int wid  = threadIdx.x >> 6;
    if (lane == 0) wsum[wid] = acc;
    __syncthreads();

    if (threadIdx.x == 0)
        out[0] = (wsum[0] + wsum[1] + wsum[2] + wsum[3]) * INV_B;  // overwrites poison
}

extern "C" void kernel_launch(void* const* d_in, const int* in_sizes, int n_in,
                              void* d_out, int out_size, void* d_ws, size_t ws_size,
                              hipStream_t stream) {
    const float4* lg  = (const float4*)d_in[0];   // logits f32 (B,2) -> B/2 float4
    const int2*   lb  = (const int2*)d_in[1];     // labels int32 (B,) -> B/2 int2
    float*        out = (float*)d_out;
    float*        ws  = (float*)d_ws;             // 2048 floats = 8 KB of scratch

    pal_loss_kernel<<<NBLOCK, NTHREAD, 0, stream>>>(lg, lb, ws);
    pal_finalize_kernel<<<1, NTHREAD, 0, stream>>>(ws, out);
}

// Round 4
// 114.956 us; speedup vs baseline: 1.1286x; 1.0041x over previous
//
#include <hip/hip_runtime.h>

// ProbabilityAdjustedLoss: B=8388608 rows of (2 logits f32, 1 label i32) -> scalar mean.
// R3 analysis: ~73% of SIMD cycles issue nothing -> all waves stalled on memory because
// the compiler sinks loads to uses (VGPR=28 => 1 load in flight per wave) AND each row
// pays ~2 IEEE f32 divisions (~20 instrs). R4: force all 16 loads in flight with
// sched_barrier(0), single-sigmoid math via sign XOR + v_rcp_f32.

#define B_TOTAL   8388608
#define INV_B     (1.0f / 8388608.0f)   // power of two, exact
#define EPS_LOSS  1e-8f

#define NBLOCK    2048
#define NTHREAD   256
#define NTOT      (NBLOCK * NTHREAD)            // 524288 threads
#define NITER     (B_TOTAL / 2 / NTOT)          // 8, exact (no tail)

__device__ __forceinline__ float row_loss(float l0, float l1, int label) {
    float d = l1 - l0;
    // p = softmax prob of the labeled class:
    //   label==0: p0 = 1/(1+e^( d))   label==1: p1 = 1/(1+e^(-d))
    // select via sign-bit XOR (labels are exactly 0/1)
    float x = __int_as_float(__float_as_int(d) ^ (label << 31));
    float e = __expf(x);                           // v_mul + v_exp
    float p = __builtin_amdgcn_rcpf(1.0f + e);     // v_add + v_rcp (~1 ulp, thr=2.5e-2)
    // weight constants selected per class (stop-gradient, forward only):
    //   stable: max(0.1, 1 - 10*max(0, p-0.95))
    //   change: max(0.5, 2 - (1/0.95)*max(0, p-0.05))
    bool chg   = (label != 0);
    float c    = chg ? 0.05f        : 0.95f;
    float b    = chg ? (1.0f/0.95f) : 10.0f;
    float a    = chg ? 2.0f         : 1.0f;
    float wmin = chg ? 0.5f         : 0.1f;
    float t = fmaxf(0.0f, p - c);
    float w = fmaxf(wmin, fmaf(-b, t, a));
    return -w * __logf(p + EPS_LOSS);
}

__global__ __launch_bounds__(NTHREAD) void pal_loss_kernel(
        const float4* __restrict__ lg,   // 2 rows per float4: (l0,l1,l0,l1)
        const int2*   __restrict__ lb,   // 2 labels per int2
        float* __restrict__ partials)    // d_ws: one float per block
{
    int tid = blockIdx.x * NTHREAD + threadIdx.x;

    // Issue ALL 16 loads (8 x dwordx4 + 8 x dwordx2, coalesced unit-stride per
    // instruction) before any compute; sched_barrier(0) stops the scheduler from
    // sinking them back to their uses (R1/R2 failure mode, VGPR=28).
    float4 L[NITER];
    int2   Y[NITER];
    #pragma unroll
    for (int k = 0; k < NITER; ++k) {
        L[k] = lg[tid + k * NTOT];
        Y[k] = lb[tid + k * NTOT];
    }
    __builtin_amdgcn_sched_barrier(0);

    float acc = 0.0f;
    #pragma unroll
    for (int k = 0; k < NITER; ++k) {
        acc += row_loss(L[k].x, L[k].y, Y[k].x);
        acc += row_loss(L[k].z, L[k].w, Y[k].y);
    }

    // wave-64 down-reduce
    #pragma unroll
    for (int off = 32; off > 0; off >>= 1)
        acc += __shfl_down(acc, off, 64);

    __shared__ float wsum[NTHREAD / 64];
    int lane = threadIdx.x & 63;
    int wid  = threadIdx.x >> 6;
    if (lane == 0) wsum[wid] = acc;
    __syncthreads();

    if (threadIdx.x == 0)
        partials[blockIdx.x] = wsum[0] + wsum[1] + wsum[2] + wsum[3];
}

__global__ __launch_bounds__(NTHREAD) void pal_finalize_kernel(
        const float* __restrict__ partials,  // 2048 floats
        float* __restrict__ out)
{
    float acc = 0.0f;
    #pragma unroll
    for (int k = 0; k < NBLOCK / NTHREAD; ++k)
        acc += partials[threadIdx.x + k * NTHREAD];

    #pragma unroll
    for (int off = 32; off > 0; off >>= 1)
        acc += __shfl_down(acc, off, 64);

    __shared__ float wsum[NTHREAD / 64];
    int lane = threadIdx.x & 63;
    int wid  = threadIdx.x >> 6;
    if (lane == 0) wsum[wid] = acc;
    __syncthreads();

    if (threadIdx.x == 0)
        out[0] = (wsum[0] + wsum[1] + wsum[2] + wsum[3]) * INV_B;  // overwrites poison
}

extern "C" void kernel_launch(void* const* d_in, const int* in_sizes, int n_in,
                              void* d_out, int out_size, void* d_ws, size_t ws_size,
                              hipStream_t stream) {
    const float4* lg  = (const float4*)d_in[0];   // logits f32 (B,2) -> B/2 float4
    const int2*   lb  = (const int2*)d_in[1];     // labels int32 (B,) -> B/2 int2
    float*        out = (float*)d_out;
    float*        ws  = (float*)d_ws;             // 2048 floats of scratch

    pal_loss_kernel<<<NBLOCK, NTHREAD, 0, stream>>>(lg, lb, ws);
    pal_finalize_kernel<<<1, NTHREAD, 0, stream>>>(ws, out);
}